// Round 1
// baseline (8318.799 us; speedup 1.0000x reference)
//
#include <hip/hip_runtime.h>

// Problem constants
constexpr int B    = 32;
constexpr int CIN  = 64;
constexpr int COUT = 128;
constexpr int T    = 300;
constexpr int V    = 25;
constexpr int TV   = T * V;            // 7500
constexpr long long NPC   = (long long)B * TV;          // 240000 per channel
constexpr long long TOTAL = (long long)B * COUT * TV;   // 30,720,000

// ---------------------------------------------------------------------------
// Kernel A: fused res_pre = w_r*x + b_r  and  h_pre = w_sp*(x) then A_hat over V, + b_sp
// (A_hat commutes with the channel matmul)
// grid (38, 32): x = t_tile (TT=8), y = b.  block 256.
// ---------------------------------------------------------------------------
__global__ __launch_bounds__(256) void kA(
    const float* __restrict__ x, const float* __restrict__ A_hat,
    const float* __restrict__ w_sp, const float* __restrict__ b_sp,
    const float* __restrict__ w_r,  const float* __restrict__ b_r,
    float* __restrict__ res_pre, float* __restrict__ h_pre)
{
  __shared__ float xs[CIN * 200];   // [c][t*25+v], TT=8 -> 200 positions
  __shared__ float As[625];
  __shared__ float ys[224];

  const int tid = threadIdx.x;
  const int b   = blockIdx.y;
  const int t0  = blockIdx.x * 8;

  for (int i = tid; i < 625; i += 256) As[i] = A_hat[i];
  for (int i = tid; i < CIN * 200; i += 256) {
    int c = i / 200, r = i % 200;
    int t = r / 25, v = r % 25;
    int tt = t0 + t;
    xs[i] = (tt < T) ? x[((b * CIN + c) * T + tt) * 25 + v] : 0.0f;
  }
  __syncthreads();

  const int  tl    = tid / 25;
  const int  vv    = tid % 25;
  const bool act   = tid < 200;
  const bool valid = act && (t0 + tl < T);

  for (int o = 0; o < COUT; ++o) {
    float accr = 0.f, accs = 0.f;
    if (act) {
      const float* wr = &w_r[o * CIN];
      const float* ws = &w_sp[o * CIN];
#pragma unroll 8
      for (int c = 0; c < CIN; ++c) {
        float xv = xs[c * 200 + tid];
        accr += wr[c] * xv;
        accs += ws[c] * xv;
      }
    }
    __syncthreads();                 // previous iteration's ys reads complete
    if (act) ys[tid] = accs;
    __syncthreads();
    if (valid) {
      float hv = b_sp[o];
      const float* Ar = &As[vv * 25];
#pragma unroll
      for (int w = 0; w < 25; ++w) hv += Ar[w] * ys[tl * 25 + w];
      int idx = ((b * COUT + o) * T + (t0 + tl)) * 25 + vv;
      res_pre[idx] = accr + b_r[o];
      h_pre[idx]   = hv;
    }
  }
}

// ---------------------------------------------------------------------------
// Kernel B: per-channel partial sums/sumsq for res_pre and h_pre.
// grid (8, 128): x = partial index p, y = channel c. block 256.
// part layout: [(c*8+p)*4 + {sum_r, sq_r, sum_s, sq_s}]
// ---------------------------------------------------------------------------
__global__ __launch_bounds__(256) void kB(
    const float* __restrict__ res_pre, const float* __restrict__ h_pre,
    float* __restrict__ part)
{
  __shared__ float red[256];
  const int tid = threadIdx.x, p = blockIdx.x, c = blockIdx.y;
  float s0 = 0, s1 = 0, s2 = 0, s3 = 0;
  for (long long i = p * 256 + tid; i < NPC; i += 8 * 256) {
    int b = (int)(i / TV), r = (int)(i % TV);
    long long addr = ((long long)b * COUT + c) * TV + r;
    float a = res_pre[addr];
    float h = h_pre[addr];
    s0 += a; s1 += a * a; s2 += h; s3 += h * h;
  }
  float vals[4] = {s0, s1, s2, s3};
  for (int j = 0; j < 4; ++j) {
    red[tid] = vals[j];
    __syncthreads();
    for (int s = 128; s > 0; s >>= 1) {
      if (tid < s) red[tid] += red[tid + s];
      __syncthreads();
    }
    if (tid == 0) part[(c * 8 + p) * 4 + j] = red[0];
    __syncthreads();
  }
}

// ---------------------------------------------------------------------------
// Kernel C: finalize res/sp BN -> scale/shift.  1 block, 128 threads.
// scales: [0]=scale_r, [128]=shift_r, [256]=scale_s, [384]=shift_s,
//         [512]=scale_t, [640]=shift_t
// ---------------------------------------------------------------------------
__global__ __launch_bounds__(128) void kC(
    const float* __restrict__ part,
    const float* __restrict__ g_r,  const float* __restrict__ be_r,
    const float* __restrict__ g_sp, const float* __restrict__ be_sp,
    float* __restrict__ scales)
{
  const int c = threadIdx.x;
  float s0 = 0, s1 = 0, s2 = 0, s3 = 0;
  for (int p = 0; p < 8; ++p) {
    const float* q = &part[(c * 8 + p) * 4];
    s0 += q[0]; s1 += q[1]; s2 += q[2]; s3 += q[3];
  }
  const float n = (float)NPC;
  float mr = s0 / n, vr = s1 / n - mr * mr;
  float ir = rsqrtf(vr + 1e-5f);
  float scr = g_r[c] * ir;
  scales[c]       = scr;
  scales[128 + c] = be_r[c] - mr * scr;
  float ms = s2 / n, vs = s3 / n - ms * ms;
  float is = rsqrtf(vs + 1e-5f);
  float scs = g_sp[c] * is;
  scales[256 + c] = scs;
  scales[384 + c] = be_sp[c] - ms * scs;
}

// ---------------------------------------------------------------------------
// Kernel E: temporal conv 9x1 over COUT channels. BN_s + ReLU fused into LDS
// staging of h_pre. Output raw conv + b_t to d_out.
// grid (8, 30, 32): x = o_tile (16 o), y = t_tile (10 t), z = b. block 256.
// ---------------------------------------------------------------------------
__global__ __launch_bounds__(256) void kE(
    const float* __restrict__ h_pre, const float* __restrict__ w_t,
    const float* __restrict__ b_t,   const float* __restrict__ scales,
    float* __restrict__ out)
{
  __shared__ float hs[32 * 450];    // [c_chunk=32][t=18][v=25]
  const int tid = threadIdx.x;
  const int o0  = blockIdx.x * 16;
  const int t0  = blockIdx.y * 10;
  const int b   = blockIdx.z;

  float acc[16];
#pragma unroll
  for (int i = 0; i < 16; ++i) acc[i] = 0.f;

  const int  tl  = tid / 25;
  const int  vv  = tid % 25;
  const bool act = tid < 250;

  for (int cc = 0; cc < 4; ++cc) {
    const int c0 = cc * 32;
    __syncthreads();                // prev chunk reads complete
    for (int i = tid; i < 32 * 450; i += 256) {
      int c = i / 450, r = i % 450;
      int t = r / 25, v = r % 25;
      int tin = t0 + t - 4;
      float val = 0.f;
      if (tin >= 0 && tin < T) {
        int ch = c0 + c;
        float sc = scales[256 + ch], sh = scales[384 + ch];
        val = fmaxf(0.f, h_pre[((b * COUT + ch) * T + tin) * 25 + v] * sc + sh);
      }
      hs[i] = val;
    }
    __syncthreads();
    if (act) {
      for (int c = 0; c < 32; ++c) {
        float hv[9];
#pragma unroll
        for (int k = 0; k < 9; ++k) hv[k] = hs[c * 450 + (tl + k) * 25 + vv];
#pragma unroll 4
        for (int ol = 0; ol < 16; ++ol) {
          const float* w = &w_t[((o0 + ol) * COUT + (c0 + c)) * 9];
          float a = acc[ol];
#pragma unroll
          for (int k = 0; k < 9; ++k) a += w[k] * hv[k];
          acc[ol] = a;
        }
      }
    }
  }
  if (act) {
#pragma unroll
    for (int ol = 0; ol < 16; ++ol) {
      int o = o0 + ol;
      out[((b * COUT + o) * T + (t0 + tl)) * 25 + vv] = acc[ol] + b_t[o];
    }
  }
}

// ---------------------------------------------------------------------------
// Kernel F: per-channel partial sums/sumsq for conv output (in d_out).
// grid (8, 128). part layout: [(c*8+p)*2 + {sum, sq}]
// ---------------------------------------------------------------------------
__global__ __launch_bounds__(256) void kF(
    const float* __restrict__ conv, float* __restrict__ part)
{
  __shared__ float red[256];
  const int tid = threadIdx.x, p = blockIdx.x, c = blockIdx.y;
  float s0 = 0, s1 = 0;
  for (long long i = p * 256 + tid; i < NPC; i += 8 * 256) {
    int b = (int)(i / TV), r = (int)(i % TV);
    float a = conv[((long long)b * COUT + c) * TV + r];
    s0 += a; s1 += a * a;
  }
  float vals[2] = {s0, s1};
  for (int j = 0; j < 2; ++j) {
    red[tid] = vals[j];
    __syncthreads();
    for (int s = 128; s > 0; s >>= 1) {
      if (tid < s) red[tid] += red[tid + s];
      __syncthreads();
    }
    if (tid == 0) part[(c * 8 + p) * 2 + j] = red[0];
    __syncthreads();
  }
}

// ---------------------------------------------------------------------------
// Kernel G: finalize temporal BN.  1 block, 128 threads.
// ---------------------------------------------------------------------------
__global__ __launch_bounds__(128) void kG(
    const float* __restrict__ part,
    const float* __restrict__ g_t, const float* __restrict__ be_t,
    float* __restrict__ scales)
{
  const int c = threadIdx.x;
  float s0 = 0, s1 = 0;
  for (int p = 0; p < 8; ++p) {
    const float* q = &part[(c * 8 + p) * 2];
    s0 += q[0]; s1 += q[1];
  }
  const float n = (float)NPC;
  float m = s0 / n, v = s1 / n - m * m;
  float iv = rsqrtf(v + 1e-5f);
  float sc = g_t[c] * iv;
  scales[512 + c] = sc;
  scales[640 + c] = be_t[c] - m * sc;
}

// ---------------------------------------------------------------------------
// Kernel H: out = relu(conv*scale_t + shift_t + res_pre*scale_r + shift_r)
// float4 vectorized (7500 % 4 == 0, so a float4 never crosses a channel plane)
// ---------------------------------------------------------------------------
__global__ __launch_bounds__(256) void kH(
    float* __restrict__ out, const float* __restrict__ res_pre,
    const float* __restrict__ scales)
{
  long long i4 = ((long long)blockIdx.x * 256 + threadIdx.x) * 4;
  if (i4 >= TOTAL) return;
  int c = (int)((i4 / TV) % COUT);
  float sct = scales[512 + c], sht = scales[640 + c];
  float scr = scales[c],       shr = scales[128 + c];
  float4 o = *reinterpret_cast<const float4*>(&out[i4]);
  float4 r = *reinterpret_cast<const float4*>(&res_pre[i4]);
  float4 y;
  y.x = fmaxf(o.x * sct + sht + r.x * scr + shr, 0.f);
  y.y = fmaxf(o.y * sct + sht + r.y * scr + shr, 0.f);
  y.z = fmaxf(o.z * sct + sht + r.z * scr + shr, 0.f);
  y.w = fmaxf(o.w * sct + sht + r.w * scr + shr, 0.f);
  *reinterpret_cast<float4*>(&out[i4]) = y;
}

// ---------------------------------------------------------------------------
extern "C" void kernel_launch(void* const* d_in, const int* in_sizes, int n_in,
                              void* d_out, int out_size, void* d_ws, size_t ws_size,
                              hipStream_t stream) {
  const float* x     = (const float*)d_in[0];
  const float* A_hat = (const float*)d_in[1];
  const float* w_sp  = (const float*)d_in[2];
  const float* b_sp  = (const float*)d_in[3];
  const float* g_sp  = (const float*)d_in[4];
  const float* be_sp = (const float*)d_in[5];
  const float* w_t   = (const float*)d_in[6];
  const float* b_t   = (const float*)d_in[7];
  const float* g_t   = (const float*)d_in[8];
  const float* be_t  = (const float*)d_in[9];
  const float* w_r   = (const float*)d_in[10];
  const float* b_r   = (const float*)d_in[11];
  const float* g_r   = (const float*)d_in[12];
  const float* be_r  = (const float*)d_in[13];
  float* out = (float*)d_out;

  float* ws       = (float*)d_ws;
  float* res_pre  = ws;                       // 30,720,000
  float* h_pre    = ws + TOTAL;               // 30,720,000
  float* part_rs  = ws + 2 * TOTAL;           // 128*8*4 = 4096
  float* part_t   = part_rs + 4096;           // 128*8*2 = 2048
  float* scales   = part_t + 2048;            // 768

  // A: fused dual matmul + graph conv
  kA<<<dim3(38, 32), 256, 0, stream>>>(x, A_hat, w_sp, b_sp, w_r, b_r,
                                       res_pre, h_pre);
  // B/C: BN stats for res & sp paths
  kB<<<dim3(8, 128), 256, 0, stream>>>(res_pre, h_pre, part_rs);
  kC<<<1, 128, 0, stream>>>(part_rs, g_r, be_r, g_sp, be_sp, scales);
  // E: temporal conv (BN_s + ReLU fused into staging)
  kE<<<dim3(8, 30, 32), 256, 0, stream>>>(h_pre, w_t, b_t, scales, out);
  // F/G: BN stats for temporal path
  kF<<<dim3(8, 128), 256, 0, stream>>>(out, part_t);
  kG<<<1, 128, 0, stream>>>(part_t, g_t, be_t, scales);
  // H: fused epilogue
  long long nv4 = TOTAL / 4;
  int blocksH = (int)((nv4 + 255) / 256);
  kH<<<blocksH, 256, 0, stream>>>(out, res_pre, scales);
}

// Round 2
// 634.094 us; speedup vs baseline: 13.1192x; 13.1192x over previous
//
#include <hip/hip_runtime.h>

// Problem constants
constexpr int B    = 32;
constexpr int CIN  = 64;
constexpr int COUT = 128;
constexpr int T    = 300;
constexpr int V    = 25;
constexpr int TV   = T * V;            // 7500
constexpr long long NPC   = (long long)B * TV;          // 240000 per channel
constexpr long long TOTAL = (long long)B * COUT * TV;   // 30,720,000

typedef short  bf16x8 __attribute__((ext_vector_type(8)));
typedef float  f32x4  __attribute__((ext_vector_type(4)));

static __device__ __forceinline__ unsigned short f2bf(float f) {
  union { float f; unsigned u; } x; x.f = f;
  unsigned r = x.u + 0x7FFFu + ((x.u >> 16) & 1u);   // RNE
  return (unsigned short)(r >> 16);
}
static __device__ __forceinline__ float bf2f(unsigned short u) {
  union { unsigned u; float f; } x; x.u = ((unsigned)u) << 16;
  return x.f;
}

// ---------------------------------------------------------------------------
// kW: temporal weights -> bf16, layout wb[o][k][c]  (147456 elems)
// ---------------------------------------------------------------------------
__global__ __launch_bounds__(256) void kW(const float* __restrict__ w_t,
                                          unsigned short* __restrict__ wb) {
  int i = blockIdx.x * 256 + threadIdx.x;
  if (i >= COUT * 9 * COUT) return;
  int c = i & 127, ok = i >> 7;
  int k = ok % 9, o = ok / 9;
  wb[i] = f2bf(w_t[(o * COUT + c) * 9 + k]);
}

// ---------------------------------------------------------------------------
// kW2: stacked 1x1 weights -> bf16, wrs[row][c], row 0-127 = w_r, 128-255 = w_sp
// ---------------------------------------------------------------------------
__global__ __launch_bounds__(256) void kW2(const float* __restrict__ w_r,
                                           const float* __restrict__ w_sp,
                                           unsigned short* __restrict__ wrs) {
  int i = blockIdx.x * 256 + threadIdx.x;
  if (i >= 256 * CIN) return;
  int c = i & 63, row = i >> 6;
  float v = (row < COUT) ? w_r[row * CIN + c] : w_sp[(row - COUT) * CIN + c];
  wrs[i] = f2bf(v);
}

// ---------------------------------------------------------------------------
// kA2: dual 1x1 conv via MFMA. M=256 stacked rows, K=64, N=64 positions/block.
// grid (118, 32). 4 waves, each 64 rows x 64 pos (4x4 fragments of 16x16x32).
// Writes res_pre fp32 (rows 0-127, +b_r) and hb bf16 (rows 128-255, +b_sp).
// ---------------------------------------------------------------------------
constexpr int NPA   = 64;
constexpr int PITA  = 72;   // shorts per pos row (64 used + 8 pad)

__global__ __launch_bounds__(256, 2) void kA2(
    const float* __restrict__ x, const unsigned short* __restrict__ wrs,
    const float* __restrict__ b_r, const float* __restrict__ b_sp,
    float* __restrict__ res_pre, unsigned short* __restrict__ hb)
{
  __shared__ unsigned short xs[NPA * PITA];   // 9216 B
  const int tid  = threadIdx.x;
  const int lane = tid & 63;
  const int wave = tid >> 6;          // 0..3 -> M quadrant
  const int b    = blockIdx.y;
  const int p0   = blockIdx.x * NPA;
  const int grp  = lane >> 4;         // 0..3
  const int l15  = lane & 15;

  // stage x tile [pos 64][c 64] -> bf16
  for (int i = tid; i < NPA * CIN; i += 256) {
    int c = i >> 6, pos = i & 63;
    int pg = p0 + pos;
    float v = (pg < TV) ? x[((b * CIN + c) * TV) + pg] : 0.f;
    xs[pos * PITA + c] = f2bf(v);
  }
  __syncthreads();

  f32x4 acc[4][4];
#pragma unroll
  for (int m = 0; m < 4; ++m)
#pragma unroll
    for (int n = 0; n < 4; ++n) acc[m][n] = (f32x4)0.f;

#pragma unroll
  for (int ks = 0; ks < 2; ++ks) {       // K-steps of 32
    const int c0 = ks * 32;
    bf16x8 af[4], bfr[4];
#pragma unroll
    for (int mi = 0; mi < 4; ++mi) {
      int row = wave * 64 + mi * 16 + l15;
      af[mi] = *(const bf16x8*)&wrs[row * CIN + c0 + grp * 8];
    }
#pragma unroll
    for (int ni = 0; ni < 4; ++ni) {
      int pos = ni * 16 + l15;
      bfr[ni] = *(const bf16x8*)&xs[pos * PITA + c0 + grp * 8];
    }
#pragma unroll
    for (int mi = 0; mi < 4; ++mi)
#pragma unroll
      for (int ni = 0; ni < 4; ++ni)
        acc[mi][ni] = __builtin_amdgcn_mfma_f32_16x16x32_bf16(
            af[mi], bfr[ni], acc[mi][ni], 0, 0, 0);
  }

  // epilogue: D col = lane&15 (pos), row = (lane>>4)*4 + reg
#pragma unroll
  for (int mi = 0; mi < 4; ++mi) {
#pragma unroll
    for (int ni = 0; ni < 4; ++ni) {
      int pos = p0 + ni * 16 + l15;
      if (pos < TV) {
#pragma unroll
        for (int r = 0; r < 4; ++r) {
          int row = wave * 64 + mi * 16 + grp * 4 + r;
          float v = acc[mi][ni][r];
          if (row < COUT) {
            res_pre[((long long)(b * COUT + row)) * TV + pos] = v + b_r[row];
          } else {
            int o = row - COUT;
            hb[((long long)(b * COUT + o)) * TV + pos] = f2bf(v + b_sp[o]);
          }
        }
      }
    }
  }
}

// ---------------------------------------------------------------------------
// kGc: graph conv over V=25, in-place on hb. h[v] = sum_w A[v][w] s[w].
// Each row-group = 10 rows of 25 (250 elems). 122880 groups total.
// ---------------------------------------------------------------------------
__global__ __launch_bounds__(256) void kGc(const float* __restrict__ A_hat,
                                           unsigned short* __restrict__ hb) {
  __shared__ float As[625];
  __shared__ float srow[250];
  const int tid = threadIdx.x;
  for (int i = tid; i < 625; i += 256) As[i] = A_hat[i];
  const int rl = tid / 25, vv = tid % 25;
  const bool act = tid < 250;
  for (long long g = blockIdx.x; g < 122880; g += gridDim.x) {
    long long base = g * 250;
    __syncthreads();
    if (act) srow[tid] = bf2f(hb[base + tid]);
    __syncthreads();
    if (act) {
      const float* Ar = &As[vv * 25];
      float a = 0.f;
#pragma unroll
      for (int w = 0; w < 25; ++w) a += Ar[w] * srow[rl * 25 + w];
      hb[base + tid] = f2bf(a);
    }
  }
}

// ---------------------------------------------------------------------------
// kB: per-channel partial sums/sumsq for res_pre (fp32) and hb (bf16).
// grid (8, 128). part layout: [(c*8+p)*4 + {sum_r, sq_r, sum_s, sq_s}]
// ---------------------------------------------------------------------------
__global__ __launch_bounds__(256) void kB(
    const float* __restrict__ res_pre, const unsigned short* __restrict__ hb,
    float* __restrict__ part)
{
  __shared__ float red[256];
  const int tid = threadIdx.x, p = blockIdx.x, c = blockIdx.y;
  float s0 = 0, s1 = 0, s2 = 0, s3 = 0;
  for (long long i = p * 256 + tid; i < NPC; i += 8 * 256) {
    int b = (int)(i / TV), r = (int)(i % TV);
    long long addr = ((long long)b * COUT + c) * TV + r;
    float a = res_pre[addr];
    float h = bf2f(hb[addr]);
    s0 += a; s1 += a * a; s2 += h; s3 += h * h;
  }
  float vals[4] = {s0, s1, s2, s3};
  for (int j = 0; j < 4; ++j) {
    red[tid] = vals[j];
    __syncthreads();
    for (int s = 128; s > 0; s >>= 1) {
      if (tid < s) red[tid] += red[tid + s];
      __syncthreads();
    }
    if (tid == 0) part[(c * 8 + p) * 4 + j] = red[0];
    __syncthreads();
  }
}

// ---------------------------------------------------------------------------
// kC: finalize res/sp BN -> scale/shift.
// scales: [0]=scale_r [128]=shift_r [256]=scale_s [384]=shift_s [512]=scale_t [640]=shift_t
// ---------------------------------------------------------------------------
__global__ __launch_bounds__(128) void kC(
    const float* __restrict__ part,
    const float* __restrict__ g_r,  const float* __restrict__ be_r,
    const float* __restrict__ g_sp, const float* __restrict__ be_sp,
    float* __restrict__ scales)
{
  const int c = threadIdx.x;
  float s0 = 0, s1 = 0, s2 = 0, s3 = 0;
  for (int p = 0; p < 8; ++p) {
    const float* q = &part[(c * 8 + p) * 4];
    s0 += q[0]; s1 += q[1]; s2 += q[2]; s3 += q[3];
  }
  const float n = (float)NPC;
  float mr = s0 / n, vr = s1 / n - mr * mr;
  float ir = rsqrtf(vr + 1e-5f);
  float scr = g_r[c] * ir;
  scales[c]       = scr;
  scales[128 + c] = be_r[c] - mr * scr;
  float ms = s2 / n, vs = s3 / n - ms * ms;
  float is = rsqrtf(vs + 1e-5f);
  float scs = g_sp[c] * is;
  scales[256 + c] = scs;
  scales[384 + c] = be_sp[c] - ms * scs;
}

// ---------------------------------------------------------------------------
// kE2: temporal conv 9x1 as implicit MFMA GEMM.
// M=128 (o), N=128 positions/block, K = 4 c-chunks x 9 shifts x 32.
// BN_s + ReLU fused into LDS staging. grid (59, 32), 4 waves (2M x 2N).
// ---------------------------------------------------------------------------
constexpr int NP    = 128;
constexpr int HALO  = 100;               // 4*25
constexpr int STAGE = NP + 2 * HALO;     // 328
constexpr int PITCH = 40;                // shorts per pos row (32 used + 8 pad)

__global__ __launch_bounds__(256, 2) void kE2(
    const unsigned short* __restrict__ hb, const unsigned short* __restrict__ wb,
    const float* __restrict__ b_t, const float* __restrict__ scales,
    float* __restrict__ out)
{
  __shared__ unsigned short hs[STAGE * PITCH];   // 26240 B
  const int tid  = threadIdx.x;
  const int lane = tid & 63;
  const int wave = tid >> 6;
  const int wm   = wave >> 1, wn = wave & 1;
  const int b    = blockIdx.y;
  const int p0   = blockIdx.x * NP;
  const int grp  = lane >> 4;
  const int l15  = lane & 15;

  f32x4 acc[4][4];
#pragma unroll
  for (int m = 0; m < 4; ++m)
#pragma unroll
    for (int n = 0; n < 4; ++n) acc[m][n] = (f32x4)0.f;

  for (int cc = 0; cc < 4; ++cc) {
    const int c0 = cc * 32;
    __syncthreads();               // previous chunk's reads complete
    // stage: [pos 328][c 32] bf16, BN_s + ReLU applied
    for (int i = tid; i < 32 * STAGE; i += 256) {
      int c = i / STAGE, pos = i - c * STAGE;
      int pg = p0 - HALO + pos;
      float v = 0.f;
      if (pg >= 0 && pg < TV) {
        int ch = c0 + c;
        float xv = bf2f(hb[((long long)(b * COUT + ch)) * TV + pg]);
        v = fmaxf(xv * scales[256 + ch] + scales[384 + ch], 0.f);
      }
      hs[pos * PITCH + c] = f2bf(v);
    }
    __syncthreads();

    for (int k = 0; k < 9; ++k) {
      bf16x8 af[4], bfr[4];
#pragma unroll
      for (int mi = 0; mi < 4; ++mi) {
        int o = wm * 64 + mi * 16 + l15;
        af[mi] = *(const bf16x8*)&wb[(o * 9 + k) * COUT + c0 + grp * 8];
      }
      const int shift = 25 * (k - 4);
#pragma unroll
      for (int ni = 0; ni < 4; ++ni) {
        int pl = HALO + wn * 64 + ni * 16 + l15 + shift;
        bfr[ni] = *(const bf16x8*)&hs[pl * PITCH + grp * 8];
      }
#pragma unroll
      for (int mi = 0; mi < 4; ++mi)
#pragma unroll
        for (int ni = 0; ni < 4; ++ni)
          acc[mi][ni] = __builtin_amdgcn_mfma_f32_16x16x32_bf16(
              af[mi], bfr[ni], acc[mi][ni], 0, 0, 0);
    }
  }

  // epilogue: conv + b_t -> out (fp32)
#pragma unroll
  for (int mi = 0; mi < 4; ++mi) {
#pragma unroll
    for (int ni = 0; ni < 4; ++ni) {
      int pos = p0 + wn * 64 + ni * 16 + l15;
      if (pos < TV) {
#pragma unroll
        for (int r = 0; r < 4; ++r) {
          int o = wm * 64 + mi * 16 + grp * 4 + r;
          out[((long long)(b * COUT + o)) * TV + pos] = acc[mi][ni][r] + b_t[o];
        }
      }
    }
  }
}

// ---------------------------------------------------------------------------
// kF: per-channel partial sums/sumsq for conv output (d_out).
// ---------------------------------------------------------------------------
__global__ __launch_bounds__(256) void kF(
    const float* __restrict__ conv, float* __restrict__ part)
{
  __shared__ float red[256];
  const int tid = threadIdx.x, p = blockIdx.x, c = blockIdx.y;
  float s0 = 0, s1 = 0;
  for (long long i = p * 256 + tid; i < NPC; i += 8 * 256) {
    int b = (int)(i / TV), r = (int)(i % TV);
    float a = conv[((long long)b * COUT + c) * TV + r];
    s0 += a; s1 += a * a;
  }
  float vals[2] = {s0, s1};
  for (int j = 0; j < 2; ++j) {
    red[tid] = vals[j];
    __syncthreads();
    for (int s = 128; s > 0; s >>= 1) {
      if (tid < s) red[tid] += red[tid + s];
      __syncthreads();
    }
    if (tid == 0) part[(c * 8 + p) * 2 + j] = red[0];
    __syncthreads();
  }
}

// ---------------------------------------------------------------------------
// kG: finalize temporal BN.
// ---------------------------------------------------------------------------
__global__ __launch_bounds__(128) void kG(
    const float* __restrict__ part,
    const float* __restrict__ g_t, const float* __restrict__ be_t,
    float* __restrict__ scales)
{
  const int c = threadIdx.x;
  float s0 = 0, s1 = 0;
  for (int p = 0; p < 8; ++p) {
    const float* q = &part[(c * 8 + p) * 2];
    s0 += q[0]; s1 += q[1];
  }
  const float n = (float)NPC;
  float m = s0 / n, v = s1 / n - m * m;
  float iv = rsqrtf(v + 1e-5f);
  float sc = g_t[c] * iv;
  scales[512 + c] = sc;
  scales[640 + c] = be_t[c] - m * sc;
}

// ---------------------------------------------------------------------------
// kH: out = relu(conv*scale_t + shift_t + res_pre*scale_r + shift_r), float4
// ---------------------------------------------------------------------------
__global__ __launch_bounds__(256) void kH(
    float* __restrict__ out, const float* __restrict__ res_pre,
    const float* __restrict__ scales)
{
  long long i4 = ((long long)blockIdx.x * 256 + threadIdx.x) * 4;
  if (i4 >= TOTAL) return;
  int c = (int)((i4 / TV) % COUT);
  float sct = scales[512 + c], sht = scales[640 + c];
  float scr = scales[c],       shr = scales[128 + c];
  float4 o = *reinterpret_cast<const float4*>(&out[i4]);
  float4 r = *reinterpret_cast<const float4*>(&res_pre[i4]);
  float4 y;
  y.x = fmaxf(o.x * sct + sht + r.x * scr + shr, 0.f);
  y.y = fmaxf(o.y * sct + sht + r.y * scr + shr, 0.f);
  y.z = fmaxf(o.z * sct + sht + r.z * scr + shr, 0.f);
  y.w = fmaxf(o.w * sct + sht + r.w * scr + shr, 0.f);
  *reinterpret_cast<float4*>(&out[i4]) = y;
}

// ---------------------------------------------------------------------------
extern "C" void kernel_launch(void* const* d_in, const int* in_sizes, int n_in,
                              void* d_out, int out_size, void* d_ws, size_t ws_size,
                              hipStream_t stream) {
  const float* x     = (const float*)d_in[0];
  const float* A_hat = (const float*)d_in[1];
  const float* w_sp  = (const float*)d_in[2];
  const float* b_sp  = (const float*)d_in[3];
  const float* g_sp  = (const float*)d_in[4];
  const float* be_sp = (const float*)d_in[5];
  const float* w_t   = (const float*)d_in[6];
  const float* b_t   = (const float*)d_in[7];
  const float* g_t   = (const float*)d_in[8];
  const float* be_t  = (const float*)d_in[9];
  const float* w_r   = (const float*)d_in[10];
  const float* b_r   = (const float*)d_in[11];
  const float* g_r   = (const float*)d_in[12];
  const float* be_r  = (const float*)d_in[13];
  float* out = (float*)d_out;

  // workspace carving (bytes; all offsets 16B-aligned)
  char* base = (char*)d_ws;
  float*          res_pre = (float*)base;                         // TOTAL f32 = 122.88 MB
  unsigned short* hb      = (unsigned short*)(base + TOTAL * 4);  // TOTAL bf16 = 61.44 MB
  unsigned short* wb      = (unsigned short*)(base + TOTAL * 6);  // 147456
  unsigned short* wrs     = wb + 147456;                          // 16384
  float*          part_rs = (float*)(base + TOTAL * 6 + (147456 + 16384) * 2); // 4096
  float*          part_t  = part_rs + 4096;                       // 2048
  float*          scales  = part_t + 2048;                        // 768

  // weight prep
  kW <<<576, 256, 0, stream>>>(w_t, wb);
  kW2<<<64,  256, 0, stream>>>(w_r, w_sp, wrs);
  // dual 1x1 conv (MFMA): res_pre fp32 + sp bf16
  kA2<<<dim3(118, 32), 256, 0, stream>>>(x, wrs, b_r, b_sp, res_pre, hb);
  // graph conv over V (in-place on hb)
  kGc<<<12288, 256, 0, stream>>>(A_hat, hb);
  // BN stats res & sp
  kB<<<dim3(8, 128), 256, 0, stream>>>(res_pre, hb, part_rs);
  kC<<<1, 128, 0, stream>>>(part_rs, g_r, be_r, g_sp, be_sp, scales);
  // temporal conv (MFMA, BN_s+ReLU fused in staging)
  kE2<<<dim3(59, 32), 256, 0, stream>>>(hb, wb, b_t, scales, out);
  // BN stats temporal
  kF<<<dim3(8, 128), 256, 0, stream>>>(out, part_t);
  kG<<<1, 128, 0, stream>>>(part_t, g_t, be_t, scales);
  // fused epilogue
  long long nv4 = TOTAL / 4;
  kH<<<(int)((nv4 + 255) / 256), 256, 0, stream>>>(out, res_pre, scales);
}

// Round 3
// 519.178 us; speedup vs baseline: 16.0230x; 1.2213x over previous
//
#include <hip/hip_runtime.h>

// Problem constants
constexpr int B    = 32;
constexpr int CIN  = 64;
constexpr int COUT = 128;
constexpr int T    = 300;
constexpr int V    = 25;
constexpr int TV   = T * V;            // 7500
constexpr long long NPC   = (long long)B * TV;          // 240000 per channel
constexpr long long TOTAL = (long long)B * COUT * TV;   // 30,720,000

typedef short          bf16x8 __attribute__((ext_vector_type(8)));
typedef float          f32x4  __attribute__((ext_vector_type(4)));
typedef unsigned short us8    __attribute__((ext_vector_type(8)));
typedef unsigned short us4    __attribute__((ext_vector_type(4)));

static __device__ __forceinline__ unsigned short f2bf(float f) {
  union { float f; unsigned u; } x; x.f = f;
  unsigned r = x.u + 0x7FFFu + ((x.u >> 16) & 1u);   // RNE
  return (unsigned short)(r >> 16);
}
static __device__ __forceinline__ float bf2f(unsigned short u) {
  union { unsigned u; float f; } x; x.u = ((unsigned)u) << 16;
  return x.f;
}

// ---------------------------------------------------------------------------
// kW: temporal weights -> bf16, layout wb2[k][cblk=c>>3][o][e=c&7]
//   idx = ((k*16 + (c>>3))*128 + o)*8 + (c&7);  16-lane-contiguous A-frag loads
// ---------------------------------------------------------------------------
__global__ __launch_bounds__(256) void kW(const float* __restrict__ w_t,
                                          unsigned short* __restrict__ wb2) {
  int i = blockIdx.x * 256 + threadIdx.x;
  if (i >= COUT * 9 * COUT) return;
  int c = i & 127, ok = i >> 7;
  int k = ok % 9, o = ok / 9;
  int idx = ((k * 16 + (c >> 3)) * 128 + o) * 8 + (c & 7);
  wb2[idx] = f2bf(w_t[(o * COUT + c) * 9 + k]);
}

// ---------------------------------------------------------------------------
// kW2: stacked 1x1 weights -> bf16, wrs[row][c], row 0-127 = w_r, 128-255 = w_sp
// ---------------------------------------------------------------------------
__global__ __launch_bounds__(256) void kW2(const float* __restrict__ w_r,
                                           const float* __restrict__ w_sp,
                                           unsigned short* __restrict__ wrs) {
  int i = blockIdx.x * 256 + threadIdx.x;
  if (i >= 256 * CIN) return;
  int c = i & 63, row = i >> 6;
  float v = (row < COUT) ? w_r[row * CIN + c] : w_sp[(row - COUT) * CIN + c];
  wrs[i] = f2bf(v);
}

// ---------------------------------------------------------------------------
// kA3: dual 1x1 conv via MFMA + fused graph conv.
// Tile: 100 pos (4 whole t's), pad to 112 for MFMA. M=256 stacked rows, K=64.
// Waves split M (64 rows each). Outputs:
//   res_pre [b][c][pos] fp32 (no bias: cancels in BN)
//   h       [b][pos][c] bf16 = A_hat-mixed spatial output (pre-BN)
// ---------------------------------------------------------------------------
constexpr int NPA  = 100;
constexpr int NPAD = 112;
constexpr int PITA = 72;   // shorts per pos row of xs

__global__ __launch_bounds__(256, 2) void kA3(
    const float* __restrict__ x, const float* __restrict__ A_hat,
    const unsigned short* __restrict__ wrs,
    float* __restrict__ res_pre, unsigned short* __restrict__ h)
{
  __shared__ unsigned short xs[NPAD * PITA];   // 16128 B
  __shared__ float          As[625];           //  2500 B
  __shared__ unsigned short hsl[NPA * 132];    // 26400 B  [pos][c] pitch 132

  const int tid  = threadIdx.x;
  const int lane = tid & 63;
  const int wave = tid >> 6;          // M quadrant (0,1 = res; 2,3 = sp)
  const int b    = blockIdx.y;
  const int p0   = blockIdx.x * NPA;
  const int grp  = lane >> 4;
  const int l15  = lane & 15;

  for (int i = tid; i < 625; i += 256) As[i] = A_hat[i];
  // stage x tile [pos][c] -> bf16 (pos > 99 zero-padded)
  for (int i = tid; i < NPAD * CIN; i += 256) {
    int c = i / NPAD, pos = i - c * NPAD;
    float v = (pos < NPA) ? x[((b * CIN + c) * TV) + p0 + pos] : 0.f;
    xs[pos * PITA + c] = f2bf(v);
  }
  __syncthreads();

  f32x4 acc[4][7];
#pragma unroll
  for (int m = 0; m < 4; ++m)
#pragma unroll
    for (int n = 0; n < 7; ++n) acc[m][n] = (f32x4)0.f;

#pragma unroll
  for (int ks = 0; ks < 2; ++ks) {
    bf16x8 af[4], bfr[7];
#pragma unroll
    for (int mi = 0; mi < 4; ++mi) {
      int row = wave * 64 + mi * 16 + l15;
      af[mi] = *(const bf16x8*)&wrs[row * CIN + ks * 32 + grp * 8];
    }
#pragma unroll
    for (int ni = 0; ni < 7; ++ni) {
      int pos = ni * 16 + l15;
      bfr[ni] = *(const bf16x8*)&xs[pos * PITA + ks * 32 + grp * 8];
    }
#pragma unroll
    for (int mi = 0; mi < 4; ++mi)
#pragma unroll
      for (int ni = 0; ni < 7; ++ni)
        acc[mi][ni] = __builtin_amdgcn_mfma_f32_16x16x32_bf16(
            af[mi], bfr[ni], acc[mi][ni], 0, 0, 0);
  }

  // epilogue: D col = l15 (pos), rows = wave*64 + mi*16 + grp*4 + r
#pragma unroll
  for (int mi = 0; mi < 4; ++mi) {
    const int rowbase = wave * 64 + mi * 16 + grp * 4;
#pragma unroll
    for (int ni = 0; ni < 7; ++ni) {
      int pos_l = ni * 16 + l15;
      if (pos_l < NPA) {
        if (rowbase < COUT) {       // res path -> global fp32
          long long base = ((long long)(b * COUT + rowbase)) * TV + p0 + pos_l;
#pragma unroll
          for (int r = 0; r < 4; ++r) res_pre[base + (long long)r * TV] = acc[mi][ni][r];
        } else {                    // sp path -> LDS tile
          int c0 = rowbase - COUT;
          us4 pk;
#pragma unroll
          for (int r = 0; r < 4; ++r) pk[r] = f2bf(acc[mi][ni][r]);
          *(us4*)&hsl[pos_l * 132 + c0] = pk;
        }
      }
    }
  }
  __syncthreads();

  // graph conv: h[v][c] = sum_w A[v][w] * sp[w][c], per t
  for (int u = tid; u < 4 * 25 * 16; u += 256) {
    int c8 = u & 15;
    int tv = u >> 4;
    int t = tv / 25, v = tv - t * 25;
    const float* Ar = &As[v * 25];
    float a[8];
#pragma unroll
    for (int e = 0; e < 8; ++e) a[e] = 0.f;
    const unsigned short* srow = &hsl[t * 25 * 132 + c8 * 8];
    for (int w = 0; w < 25; ++w) {
      float aw = Ar[w];
      us8 s = *(const us8*)&srow[w * 132];
#pragma unroll
      for (int e = 0; e < 8; ++e) a[e] += aw * bf2f(s[e]);
    }
    us8 pk;
#pragma unroll
    for (int e = 0; e < 8; ++e) pk[e] = f2bf(a[e]);
    *(us8*)&h[((long long)(b * TV + p0 + t * 25 + v)) * COUT + c8 * 8] = pk;
  }
}

// ---------------------------------------------------------------------------
// kBh: per-channel sum/sumsq of h ([b][pos][c] bf16). grid (64, 4).
// block (rs, cq): rows rs*3750..+3750, channels cq*32..+31.
// part_h[(cq*64+rs)*64 + cl*2 + {0,1}]   (lives in d_out scratch)
// ---------------------------------------------------------------------------
__global__ __launch_bounds__(256) void kBh(const unsigned short* __restrict__ h,
                                           float* __restrict__ part_h) {
  __shared__ float red[256 * 16];
  const int tid = threadIdx.x;
  const int rs = blockIdx.x, cq = blockIdx.y;
  const int cl8 = tid & 3, rl = tid >> 2;          // 4 c-slots x 64 row-lanes
  const long long r0 = (long long)rs * 3750;
  float s[8], q[8];
#pragma unroll
  for (int e = 0; e < 8; ++e) { s[e] = 0.f; q[e] = 0.f; }
  for (int r = rl; r < 3750; r += 64) {
    us8 v = *(const us8*)&h[(r0 + r) * COUT + cq * 32 + cl8 * 8];
#pragma unroll
    for (int e = 0; e < 8; ++e) {
      float f = bf2f(v[e]);
      s[e] += f; q[e] += f * f;
    }
  }
#pragma unroll
  for (int e = 0; e < 8; ++e) { red[tid * 16 + e] = s[e]; red[tid * 16 + 8 + e] = q[e]; }
  __syncthreads();
  if (tid < 32) {
    int c = tid >> 3, e = tid & 7;   // c-slot, elem
    float ss = 0.f, qq = 0.f;
    for (int r = 0; r < 64; ++r) {
      const float* rr = &red[(r * 4 + c) * 16];
      ss += rr[e]; qq += rr[8 + e];
    }
    int cl = c * 8 + e;
    int blk = cq * 64 + rs;
    part_h[blk * 64 + cl * 2]     = ss;
    part_h[blk * 64 + cl * 2 + 1] = qq;
  }
}

// ---------------------------------------------------------------------------
// kBr: per-channel sum/sumsq of res_pre ([b][c][pos] fp32). grid (8, 128).
// part_r[(c*8+p)*2 + {0,1}]  (lives in d_out scratch)
// ---------------------------------------------------------------------------
__global__ __launch_bounds__(256) void kBr(const float* __restrict__ res_pre,
                                           float* __restrict__ part_r) {
  __shared__ float red[256];
  const int tid = threadIdx.x, p = blockIdx.x, c = blockIdx.y;
  float s0 = 0, s1 = 0;
  for (long long i = p * 256 + tid; i < NPC; i += 8 * 256) {
    int b = (int)(i / TV), r = (int)(i % TV);
    float a = res_pre[((long long)b * COUT + c) * TV + r];
    s0 += a; s1 += a * a;
  }
  float vals[2] = {s0, s1};
  for (int j = 0; j < 2; ++j) {
    red[tid] = vals[j];
    __syncthreads();
    for (int sft = 128; sft > 0; sft >>= 1) {
      if (tid < sft) red[tid] += red[tid + sft];
      __syncthreads();
    }
    if (tid == 0) part_r[(c * 8 + p) * 2 + j] = red[0];
    __syncthreads();
  }
}

// ---------------------------------------------------------------------------
// kC2: finalize res & sp BN -> scale/shift.
// scales: [0]=scale_r [128]=shift_r [256]=scale_s [384]=shift_s [512]=scale_t [640]=shift_t
// ---------------------------------------------------------------------------
__global__ __launch_bounds__(128) void kC2(
    const float* __restrict__ part_h, const float* __restrict__ part_r,
    const float* __restrict__ g_r,  const float* __restrict__ be_r,
    const float* __restrict__ g_sp, const float* __restrict__ be_sp,
    float* __restrict__ scales)
{
  const int c = threadIdx.x;
  const float n = (float)NPC;
  float s0 = 0, s1 = 0;
  for (int p = 0; p < 8; ++p) { s0 += part_r[(c * 8 + p) * 2]; s1 += part_r[(c * 8 + p) * 2 + 1]; }
  float mr = s0 / n, vr = s1 / n - mr * mr;
  float scr = g_r[c] * rsqrtf(vr + 1e-5f);
  scales[c]       = scr;
  scales[128 + c] = be_r[c] - mr * scr;

  float t0 = 0, t1 = 0;
  int cq = c >> 5, cl = c & 31;
  for (int rs = 0; rs < 64; ++rs) {
    const float* q = &part_h[(cq * 64 + rs) * 64 + cl * 2];
    t0 += q[0]; t1 += q[1];
  }
  float ms = t0 / n, vs = t1 / n - ms * ms;
  float scs = g_sp[c] * rsqrtf(vs + 1e-5f);
  scales[256 + c] = scs;
  scales[384 + c] = be_sp[c] - ms * scs;
}

// ---------------------------------------------------------------------------
// kP: in-place BN_s + ReLU on h ([b][pos][c] bf16), ushort8 vectorized.
// ---------------------------------------------------------------------------
__global__ __launch_bounds__(256) void kP(unsigned short* __restrict__ h,
                                          const float* __restrict__ scales) {
  const int c0 = (threadIdx.x & 15) * 8;
  float sc[8], sh[8];
#pragma unroll
  for (int e = 0; e < 8; ++e) { sc[e] = scales[256 + c0 + e]; sh[e] = scales[384 + c0 + e]; }
  const long long NU = TOTAL / 8;
  for (long long u = (long long)blockIdx.x * 256 + threadIdx.x; u < NU;
       u += (long long)gridDim.x * 256) {
    us8 v = *(const us8*)&h[u * 8];
    us8 o;
#pragma unroll
    for (int e = 0; e < 8; ++e) {
      float f = fmaxf(bf2f(v[e]) * sc[e] + sh[e], 0.f);
      o[e] = f2bf(f);
    }
    *(us8*)&h[u * 8] = o;
  }
}

// ---------------------------------------------------------------------------
// kE3: temporal conv 9x1 as implicit MFMA GEMM.
// B-tile [pos 328][c 64] bf16 in LDS, 128B rows, XOR slot swizzle (T2).
// Staging: 16B vectorized load + ds_write_b128, pure copy (BN pre-applied).
// A-frags streamed from L2 (wb2, 16-lane contiguous). grid (59, 32).
// ---------------------------------------------------------------------------
constexpr int NP    = 128;
constexpr int HALO  = 100;               // 4*25
constexpr int STAGE = NP + 2 * HALO;     // 328

__global__ __launch_bounds__(256, 3) void kE3(
    const unsigned short* __restrict__ h, const unsigned short* __restrict__ wb2,
    float* __restrict__ out)
{
  __shared__ unsigned short hs[STAGE * 64];   // 41984 B
  const int tid  = threadIdx.x;
  const int lane = tid & 63;
  const int wave = tid >> 6;
  const int wm   = wave >> 1, wn = wave & 1;
  const int b    = blockIdx.y;
  const int p0   = blockIdx.x * NP;
  const int grp  = lane >> 4;
  const int l15  = lane & 15;
  const int slot = tid & 7;

  f32x4 acc[4][4];
#pragma unroll
  for (int m = 0; m < 4; ++m)
#pragma unroll
    for (int n = 0; n < 4; ++n) acc[m][n] = (f32x4)0.f;

  for (int cc = 0; cc < 2; ++cc) {
    if (cc) __syncthreads();             // previous chunk reads complete
    const int c0 = cc * 64;
    // stage: [pos][64c], swizzled 16B slots
    for (int i = tid; i < STAGE * 8; i += 256) {
      int pos = i >> 3;
      int pg = p0 - HALO + pos;
      us8 v = (us8)(unsigned short)0;
      if (pg >= 0 && pg < TV)
        v = *(const us8*)&h[((long long)b * TV + pg) * COUT + c0 + slot * 8];
      int si = (pos << 6) + ((slot ^ (pos & 7)) << 3);
      *(us8*)&hs[si] = v;
    }
    __syncthreads();

    for (int k = 0; k < 9; ++k) {
      const int plb = HALO + wn * 64 + 25 * (k - 4) + l15;
#pragma unroll
      for (int ks = 0; ks < 2; ++ks) {
        bf16x8 af[4], bfr[4];
#pragma unroll
        for (int mi = 0; mi < 4; ++mi) {
          int o = wm * 64 + mi * 16 + l15;
          af[mi] = *(const bf16x8*)&wb2[((k * 16 + cc * 8 + ks * 4 + grp) * 128 + o) * 8];
        }
#pragma unroll
        for (int ni = 0; ni < 4; ++ni) {
          int pl = plb + ni * 16;
          int si = (pl << 6) + (((ks * 4 + grp) ^ (pl & 7)) << 3);
          bfr[ni] = *(const bf16x8*)&hs[si];
        }
#pragma unroll
        for (int mi = 0; mi < 4; ++mi)
#pragma unroll
          for (int ni = 0; ni < 4; ++ni)
            acc[mi][ni] = __builtin_amdgcn_mfma_f32_16x16x32_bf16(
                af[mi], bfr[ni], acc[mi][ni], 0, 0, 0);
      }
    }
  }

  // epilogue: raw conv -> out fp32 (bias dropped: cancels in BN)
#pragma unroll
  for (int mi = 0; mi < 4; ++mi) {
#pragma unroll
    for (int ni = 0; ni < 4; ++ni) {
      int pos = p0 + wn * 64 + ni * 16 + l15;
      if (pos < TV) {
#pragma unroll
        for (int r = 0; r < 4; ++r) {
          int o = wm * 64 + mi * 16 + grp * 4 + r;
          out[((long long)(b * COUT + o)) * TV + pos] = acc[mi][ni][r];
        }
      }
    }
  }
}

// ---------------------------------------------------------------------------
// kF: per-channel partial sums/sumsq for conv output (d_out). grid (8,128).
// ---------------------------------------------------------------------------
__global__ __launch_bounds__(256) void kF(
    const float* __restrict__ conv, float* __restrict__ part)
{
  __shared__ float red[256];
  const int tid = threadIdx.x, p = blockIdx.x, c = blockIdx.y;
  float s0 = 0, s1 = 0;
  for (long long i = p * 256 + tid; i < NPC; i += 8 * 256) {
    int b = (int)(i / TV), r = (int)(i % TV);
    float a = conv[((long long)b * COUT + c) * TV + r];
    s0 += a; s1 += a * a;
  }
  float vals[2] = {s0, s1};
  for (int j = 0; j < 2; ++j) {
    red[tid] = vals[j];
    __syncthreads();
    for (int sft = 128; sft > 0; sft >>= 1) {
      if (tid < sft) red[tid] += red[tid + sft];
      __syncthreads();
    }
    if (tid == 0) part[(c * 8 + p) * 2 + j] = red[0];
    __syncthreads();
  }
}

// ---------------------------------------------------------------------------
// kG: finalize temporal BN.
// ---------------------------------------------------------------------------
__global__ __launch_bounds__(128) void kG(
    const float* __restrict__ part,
    const float* __restrict__ g_t, const float* __restrict__ be_t,
    float* __restrict__ scales)
{
  const int c = threadIdx.x;
  float s0 = 0, s1 = 0;
  for (int p = 0; p < 8; ++p) {
    const float* q = &part[(c * 8 + p) * 2];
    s0 += q[0]; s1 += q[1];
  }
  const float n = (float)NPC;
  float m = s0 / n, v = s1 / n - m * m;
  float sc = g_t[c] * rsqrtf(v + 1e-5f);
  scales[512 + c] = sc;
  scales[640 + c] = be_t[c] - m * sc;
}

// ---------------------------------------------------------------------------
// kH: out = relu(conv*scale_t + shift_t + res_pre*scale_r + shift_r), float4
// ---------------------------------------------------------------------------
__global__ __launch_bounds__(256) void kH(
    float* __restrict__ out, const float* __restrict__ res_pre,
    const float* __restrict__ scales)
{
  long long i4 = ((long long)blockIdx.x * 256 + threadIdx.x) * 4;
  if (i4 >= TOTAL) return;
  int c = (int)((i4 / TV) % COUT);
  float sct = scales[512 + c], sht = scales[640 + c];
  float scr = scales[c],       shr = scales[128 + c];
  float4 o = *reinterpret_cast<const float4*>(&out[i4]);
  float4 r = *reinterpret_cast<const float4*>(&res_pre[i4]);
  float4 y;
  y.x = fmaxf(o.x * sct + sht + r.x * scr + shr, 0.f);
  y.y = fmaxf(o.y * sct + sht + r.y * scr + shr, 0.f);
  y.z = fmaxf(o.z * sct + sht + r.z * scr + shr, 0.f);
  y.w = fmaxf(o.w * sct + sht + r.w * scr + shr, 0.f);
  *reinterpret_cast<float4*>(&out[i4]) = y;
}

// ---------------------------------------------------------------------------
extern "C" void kernel_launch(void* const* d_in, const int* in_sizes, int n_in,
                              void* d_out, int out_size, void* d_ws, size_t ws_size,
                              hipStream_t stream) {
  const float* x     = (const float*)d_in[0];
  const float* A_hat = (const float*)d_in[1];
  const float* w_sp  = (const float*)d_in[2];
  const float* g_sp  = (const float*)d_in[4];
  const float* be_sp = (const float*)d_in[5];
  const float* w_t   = (const float*)d_in[6];
  const float* g_t   = (const float*)d_in[8];
  const float* be_t  = (const float*)d_in[9];
  const float* w_r   = (const float*)d_in[10];
  const float* g_r   = (const float*)d_in[12];
  const float* be_r  = (const float*)d_in[13];
  float* out = (float*)d_out;

  // workspace carving
  char* base = (char*)d_ws;
  float*          res_pre = (float*)base;                           // 122.88 MB
  unsigned short* h       = (unsigned short*)(base + (size_t)TOTAL * 4);  // 61.44 MB
  unsigned short* wb2     = (unsigned short*)(base + (size_t)TOTAL * 6);  // 294912 B
  unsigned short* wrs     = wb2 + 147456;                           // 32768 B
  float*          part_t  = (float*)(base + (size_t)TOTAL * 6 + 294912 + 32768); // 8 KB
  float*          scales  = part_t + 2048;                          // 3 KB

  // d_out as scratch for pre-kE3 stats partials (kE3 overwrites all of d_out)
  float* part_h = (float*)d_out;            // 16384 floats
  float* part_r = (float*)d_out + 16384;    //  2048 floats

  // weight prep
  kW <<<576, 256, 0, stream>>>(w_t, wb2);
  kW2<<<64,  256, 0, stream>>>(w_r, w_sp, wrs);
  // dual 1x1 conv (MFMA) + fused graph conv
  kA3<<<dim3(75, 32), 256, 0, stream>>>(x, A_hat, wrs, res_pre, h);
  // BN stats (res + sp)
  kBh<<<dim3(64, 4), 256, 0, stream>>>(h, part_h);
  kBr<<<dim3(8, 128), 256, 0, stream>>>(res_pre, part_r);
  kC2<<<1, 128, 0, stream>>>(part_h, part_r, g_r, be_r, g_sp, be_sp, scales);
  // in-place BN_s + ReLU
  kP<<<2048, 256, 0, stream>>>(h, scales);
  // temporal conv (MFMA)
  kE3<<<dim3(59, 32), 256, 0, stream>>>(h, wb2, out);
  // BN stats temporal
  kF<<<dim3(8, 128), 256, 0, stream>>>(out, part_t);
  kG<<<1, 128, 0, stream>>>(part_t, g_t, be_t, scales);
  // fused epilogue
  long long nv4 = TOTAL / 4;
  kH<<<(int)((nv4 + 255) / 256), 256, 0, stream>>>(out, res_pre, scales);
}

// Round 5
// 297.647 us; speedup vs baseline: 27.9485x; 1.7443x over previous
//
#include <hip/hip_runtime.h>

// Problem constants
constexpr int B    = 32;
constexpr int CIN  = 64;
constexpr int COUT = 128;
constexpr int T    = 300;
constexpr int V    = 25;
constexpr int TV   = T * V;            // 7500
constexpr long long NPC   = (long long)B * TV;          // 240000 per channel
constexpr long long TOTAL = (long long)B * COUT * TV;   // 30,720,000

typedef short          bf16x8 __attribute__((ext_vector_type(8)));
typedef float          f32x4  __attribute__((ext_vector_type(4)));
typedef unsigned short us8    __attribute__((ext_vector_type(8)));
typedef unsigned short us4    __attribute__((ext_vector_type(4)));

static __device__ __forceinline__ unsigned short f2bf(float f) {
  union { float f; unsigned u; } x; x.f = f;
  unsigned r = x.u + 0x7FFFu + ((x.u >> 16) & 1u);   // RNE
  return (unsigned short)(r >> 16);
}
static __device__ __forceinline__ float bf2f(unsigned short u) {
  union { unsigned u; float f; } x; x.u = ((unsigned)u) << 16;
  return x.f;
}

// swizzled offsets (in shorts). Rows are 128B (64 shorts) / 256B (128 shorts),
// XOR at 16B-slot granularity -> >=2-way-free LDS access patterns.
static __device__ __forceinline__ int xoff(int pos, int c) {      // [pos][c<64]
  return pos * 64 + ((((c >> 3)) ^ (pos & 7)) << 3) + (c & 7);
}
static __device__ __forceinline__ int soff(int c, int pw) {       // [c][pw<128]
  return c * 128 + ((((pw >> 3)) ^ (c & 7)) << 3) + (pw & 7);
}

// ---------------------------------------------------------------------------
// kWT: temporal weights -> bf16, wb2[k][cblk=c>>3][o][e=c&7]
// ---------------------------------------------------------------------------
__global__ __launch_bounds__(256) void kWT(const float* __restrict__ w_t,
                                           unsigned short* __restrict__ wb2) {
  int i = blockIdx.x * 256 + threadIdx.x;
  if (i >= COUT * 9 * COUT) return;
  int c = i & 127, ok = i >> 7;
  int k = ok % 9, o = ok / 9;
  int idx = ((k * 16 + (c >> 3)) * 128 + o) * 8 + (c & 7);
  wb2[idx] = f2bf(w_t[(o * COUT + c) * 9 + k]);
}

// ---------------------------------------------------------------------------
// kW2: stacked 1x1 weights -> bf16, wrs2[cblk][row][e]; rows 0-127 w_r, 128-255 w_sp
// ---------------------------------------------------------------------------
__global__ __launch_bounds__(256) void kW2(const float* __restrict__ w_r,
                                           const float* __restrict__ w_sp,
                                           unsigned short* __restrict__ wrs2) {
  int i = blockIdx.x * 256 + threadIdx.x;
  if (i >= 256 * CIN) return;
  int c = i & 63, row = i >> 6;
  float v = (row < COUT) ? w_r[row * CIN + c] : w_sp[(row - COUT) * CIN + c];
  wrs2[((c >> 3) * 256 + row) * 8 + (c & 7)] = f2bf(v);
}

// ---------------------------------------------------------------------------
// kWB: block-diagonal graph matrix, bdt[pv][pw] (112x128 bf16):
//   bdt[pv][pw] = A_hat[pv%25][pw%25] if pv,pw<100 and same t-block, else 0.
// Consumed as the B-operand of the mix GEMM (col pv, k=pw contiguous).
// ---------------------------------------------------------------------------
__global__ __launch_bounds__(256) void kWB(const float* __restrict__ A_hat,
                                           unsigned short* __restrict__ bdt) {
  int i = blockIdx.x * 256 + threadIdx.x;
  if (i >= 112 * 128) return;
  int pv = i >> 7, pw = i & 127;
  float v = 0.f;
  if (pv < 100 && pw < 100 && (pv / 25) == (pw / 25))
    v = A_hat[(pv % 25) * 25 + (pw % 25)];
  bdt[i] = f2bf(v);
}

// ---------------------------------------------------------------------------
// kA4: all-MFMA spatial front-end. Per block: 100-pos tile (4 whole t's) of one b.
//  1) stage x -> xs[c][pw] (mix layout) + xsp[pos][c] (channel layout), bf16
//  2) mix GEMM:   ax[c][pv] = sum_pw x[c][pw]*G[pv][pw]   (sparse k-steps)
//  3) channel GEMMs: res = w_r*x (from xsp), h = w_sp*ax (from axsp)
//  res -> resb bf16 [b][c][pos];  h -> global bf16 [b][pos][c]
// grid (75, 32), 4 waves.
// ---------------------------------------------------------------------------
__global__ __launch_bounds__(256, 2) void kA4(
    const float* __restrict__ x, const unsigned short* __restrict__ bdt,
    const unsigned short* __restrict__ wrs2,
    unsigned short* __restrict__ resb, unsigned short* __restrict__ h)
{
  __shared__ unsigned short xs[64 * 128];    // 16 KB  [c][pw]  swizzled
  __shared__ unsigned short xsp[112 * 64];   // 14 KB  [pos][c] swizzled
  __shared__ unsigned short axsp[112 * 64];  // 14 KB  [pv][c]  swizzled

  const int tid  = threadIdx.x;
  const int lane = tid & 63;
  const int wave = tid >> 6;
  const int b    = blockIdx.y;
  const int p0   = blockIdx.x * 100;
  const int grp  = lane >> 4;
  const int l15  = lane & 15;

  // ---- stage: unit = (c4, pos): 4 scalar global loads (lane-coalesced along
  // pos) -> 4 b16 writes to xs (2-way free) + 1 us4 write to xsp (4-way).
  for (int u = tid; u < 16 * 128; u += 256) {
    int pos = u & 127, c4 = u >> 7;
    int c0 = c4 * 4;
    float v0 = 0.f, v1 = 0.f, v2 = 0.f, v3 = 0.f;
    if (pos < 100) {
      const float* xp = &x[(b * CIN + c0) * TV + p0 + pos];
      v0 = xp[0]; v1 = xp[TV]; v2 = xp[2 * TV]; v3 = xp[3 * TV];
    }
    unsigned short b0 = f2bf(v0), b1 = f2bf(v1), b2 = f2bf(v2), b3 = f2bf(v3);
    xs[soff(c0,     pos)] = b0;
    xs[soff(c0 + 1, pos)] = b1;
    xs[soff(c0 + 2, pos)] = b2;
    xs[soff(c0 + 3, pos)] = b3;
    if (pos < 112) {
      us4 pk = {b0, b1, b2, b3};
      *(us4*)&xsp[xoff(pos, c0)] = pk;
    }
  }
  __syncthreads();

  // ---- mix GEMM: wave owns c-rows wave*16..+15, all 7 pv-tiles, sparse k.
  bf16x8 xf[4];
#pragma unroll
  for (int ks = 0; ks < 4; ++ks)
    xf[ks] = *(const bf16x8*)&xs[soff(wave * 16 + l15, ks * 32 + grp * 8)];

  {
    f32x4 macc[7];
#pragma unroll
    for (int ni = 0; ni < 7; ++ni) macc[ni] = (f32x4)0.f;
    // pv-tile ni -> t range -> pw range -> k-step range (VERIFIED per-tile):
    // ni: 0:{0} 1:{0,1} 2:{0,1} 3:{0,1,2} 4:{1,2,3} 5:{2,3} 6:{2,3}
    const int kst[7] = {0, 0, 0, 0, 1, 2, 2};
    const int kcn[7] = {1, 2, 2, 3, 3, 2, 2};
#pragma unroll
    for (int ni = 0; ni < 7; ++ni) {
      for (int kk = 0; kk < kcn[ni]; ++kk) {
        int ks = kst[ni] + kk;
        bf16x8 gf = *(const bf16x8*)&bdt[(ni * 16 + l15) * 128 + ks * 32 + grp * 8];
        macc[ni] = __builtin_amdgcn_mfma_f32_16x16x32_bf16(xf[ks], gf, macc[ni], 0, 0, 0);
      }
    }
    // D: col pv = l15, row c = wave*16 + grp*4 + r  -> axsp[pv][c]
#pragma unroll
    for (int ni = 0; ni < 7; ++ni) {
#pragma unroll
      for (int r = 0; r < 4; ++r)
        axsp[xoff(ni * 16 + l15, wave * 16 + grp * 4 + r)] = f2bf(macc[ni][r]);
    }
  }
  __syncthreads();

  // ---- channel GEMMs: stacked rows; waves 0,1 res (B=xsp), waves 2,3 sp (B=axsp)
  const unsigned short* bsrc = (wave < 2) ? xsp : axsp;
  f32x4 acc[4][7];
#pragma unroll
  for (int m = 0; m < 4; ++m)
#pragma unroll
    for (int n = 0; n < 7; ++n) acc[m][n] = (f32x4)0.f;

#pragma unroll
  for (int ks = 0; ks < 2; ++ks) {
    bf16x8 af[4], bfr[7];
#pragma unroll
    for (int mi = 0; mi < 4; ++mi) {
      int row = wave * 64 + mi * 16 + l15;
      af[mi] = *(const bf16x8*)&wrs2[((ks * 4 + grp) * 256 + row) * 8];
    }
#pragma unroll
    for (int ni = 0; ni < 7; ++ni)
      bfr[ni] = *(const bf16x8*)&bsrc[xoff(ni * 16 + l15, ks * 32 + grp * 8)];
#pragma unroll
    for (int mi = 0; mi < 4; ++mi)
#pragma unroll
      for (int ni = 0; ni < 7; ++ni)
        acc[mi][ni] = __builtin_amdgcn_mfma_f32_16x16x32_bf16(
            af[mi], bfr[ni], acc[mi][ni], 0, 0, 0);
  }

  // ---- epilogue
  if (wave < 2) {        // res -> resb bf16 [b][c][pos]
#pragma unroll
    for (int mi = 0; mi < 4; ++mi) {
#pragma unroll
      for (int ni = 0; ni < 7; ++ni) {
        int pos = ni * 16 + l15;
        if (pos < 100) {
#pragma unroll
          for (int r = 0; r < 4; ++r) {
            int c = wave * 64 + mi * 16 + grp * 4 + r;
            resb[((long long)(b * COUT + c)) * TV + p0 + pos] = f2bf(acc[mi][ni][r]);
          }
        }
      }
    }
  } else {               // h -> [b][pos][c] bf16, us4 packs of 4 o's
#pragma unroll
    for (int mi = 0; mi < 4; ++mi) {
      int o0 = (wave - 2) * 64 + mi * 16 + grp * 4;
#pragma unroll
      for (int ni = 0; ni < 7; ++ni) {
        int pos = ni * 16 + l15;
        if (pos < 100) {
          us4 pk;
#pragma unroll
          for (int r = 0; r < 4; ++r) pk[r] = f2bf(acc[mi][ni][r]);
          *(us4*)&h[((long long)(b * TV + p0 + pos)) * COUT + o0] = pk;
        }
      }
    }
  }
}

// ---------------------------------------------------------------------------
// kBh: per-channel sum/sumsq of h ([b][pos][c] bf16). grid (64, 4).
// part_h[(cq*64+rs)*64 + cl*2 + {0,1}]
// ---------------------------------------------------------------------------
__global__ __launch_bounds__(256) void kBh(const unsigned short* __restrict__ h,
                                           float* __restrict__ part_h) {
  __shared__ float red[256 * 16];
  const int tid = threadIdx.x;
  const int rs = blockIdx.x, cq = blockIdx.y;
  const int cl8 = tid & 3, rl = tid >> 2;
  const long long r0 = (long long)rs * 3750;
  float s[8], q[8];
#pragma unroll
  for (int e = 0; e < 8; ++e) { s[e] = 0.f; q[e] = 0.f; }
  for (int r = rl; r < 3750; r += 64) {
    us8 v = *(const us8*)&h[(r0 + r) * COUT + cq * 32 + cl8 * 8];
#pragma unroll
    for (int e = 0; e < 8; ++e) {
      float f = bf2f(v[e]);
      s[e] += f; q[e] += f * f;
    }
  }
#pragma unroll
  for (int e = 0; e < 8; ++e) { red[tid * 16 + e] = s[e]; red[tid * 16 + 8 + e] = q[e]; }
  __syncthreads();
  if (tid < 32) {
    int c = tid >> 3, e = tid & 7;
    float ss = 0.f, qq = 0.f;
    for (int r = 0; r < 64; ++r) {
      const float* rr = &red[(r * 4 + c) * 16];
      ss += rr[e]; qq += rr[8 + e];
    }
    int cl = c * 8 + e;
    int blk = cq * 64 + rs;
    part_h[blk * 64 + cl * 2]     = ss;
    part_h[blk * 64 + cl * 2 + 1] = qq;
  }
}

// ---------------------------------------------------------------------------
// kBr: per-channel sum/sumsq of resb (bf16 [b][c][pos]). grid (8, 128).
// ---------------------------------------------------------------------------
__global__ __launch_bounds__(256) void kBr(const unsigned short* __restrict__ resb,
                                           float* __restrict__ part_r) {
  __shared__ float red[256];
  const int tid = threadIdx.x, p = blockIdx.x, c = blockIdx.y;
  float s0 = 0, s1 = 0;
  for (int b = 0; b < B; ++b) {
    const us4* plane = (const us4*)&resb[((long long)(b * COUT + c)) * TV];
    for (int u = p * 256 + tid; u < 1875; u += 2048) {
      us4 v = plane[u];
#pragma unroll
      for (int e = 0; e < 4; ++e) {
        float f = bf2f(v[e]);
        s0 += f; s1 += f * f;
      }
    }
  }
  float vals[2] = {s0, s1};
  for (int j = 0; j < 2; ++j) {
    red[tid] = vals[j];
    __syncthreads();
    for (int sft = 128; sft > 0; sft >>= 1) {
      if (tid < sft) red[tid] += red[tid + sft];
      __syncthreads();
    }
    if (tid == 0) part_r[(c * 8 + p) * 2 + j] = red[0];
    __syncthreads();
  }
}

// ---------------------------------------------------------------------------
// kC2: finalize res & sp BN -> scale/shift.
// scales: [0]=sc_r [128]=sh_r [256]=sc_s [384]=sh_s [512]=sc_t [640]=sh_t
// ---------------------------------------------------------------------------
__global__ __launch_bounds__(128) void kC2(
    const float* __restrict__ part_h, const float* __restrict__ part_r,
    const float* __restrict__ g_r,  const float* __restrict__ be_r,
    const float* __restrict__ g_sp, const float* __restrict__ be_sp,
    float* __restrict__ scales)
{
  const int c = threadIdx.x;
  const float n = (float)NPC;
  float s0 = 0, s1 = 0;
  for (int p = 0; p < 8; ++p) { s0 += part_r[(c * 8 + p) * 2]; s1 += part_r[(c * 8 + p) * 2 + 1]; }
  float mr = s0 / n, vr = s1 / n - mr * mr;
  float scr = g_r[c] * rsqrtf(vr + 1e-5f);
  scales[c]       = scr;
  scales[128 + c] = be_r[c] - mr * scr;

  float t0 = 0, t1 = 0;
  int cq = c >> 5, cl = c & 31;
  for (int rs = 0; rs < 64; ++rs) {
    const float* q = &part_h[(cq * 64 + rs) * 64 + cl * 2];
    t0 += q[0]; t1 += q[1];
  }
  float ms = t0 / n, vs = t1 / n - ms * ms;
  float scs = g_sp[c] * rsqrtf(vs + 1e-5f);
  scales[256 + c] = scs;
  scales[384 + c] = be_sp[c] - ms * scs;
}

// ---------------------------------------------------------------------------
// kE4: temporal conv 9x1 as implicit MFMA GEMM; BN_s+ReLU fused into the
// vectorized swizzled staging. Output bf16 -> cvb. grid (59, 32), 4 waves.
// ---------------------------------------------------------------------------
constexpr int NP    = 128;
constexpr int HALO  = 100;               // 4*25
constexpr int STAGE = NP + 2 * HALO;     // 328

__global__ __launch_bounds__(256, 3) void kE4(
    const unsigned short* __restrict__ h, const unsigned short* __restrict__ wb2,
    const float* __restrict__ scales, unsigned short* __restrict__ cvb)
{
  __shared__ unsigned short hs[STAGE * 64];   // 41984 B
  const int tid  = threadIdx.x;
  const int lane = tid & 63;
  const int wave = tid >> 6;
  const int wm   = wave >> 1, wn = wave & 1;
  const int b    = blockIdx.y;
  const int p0   = blockIdx.x * NP;
  const int grp  = lane >> 4;
  const int l15  = lane & 15;
  const int slot = tid & 7;

  f32x4 acc[4][4];
#pragma unroll
  for (int m = 0; m < 4; ++m)
#pragma unroll
    for (int n = 0; n < 4; ++n) acc[m][n] = (f32x4)0.f;

  for (int cc = 0; cc < 2; ++cc) {
    if (cc) __syncthreads();
    const int c0 = cc * 64;
    float sc[8], sh[8];
#pragma unroll
    for (int e = 0; e < 8; ++e) {
      sc[e] = scales[256 + c0 + slot * 8 + e];
      sh[e] = scales[384 + c0 + slot * 8 + e];
    }
    for (int i = tid; i < STAGE * 8; i += 256) {
      int pos = i >> 3;
      int pg = p0 - HALO + pos;
      us8 o = (us8)(unsigned short)0;
      if (pg >= 0 && pg < TV) {
        us8 v = *(const us8*)&h[((long long)b * TV + pg) * COUT + c0 + slot * 8];
#pragma unroll
        for (int e = 0; e < 8; ++e)
          o[e] = f2bf(fmaxf(bf2f(v[e]) * sc[e] + sh[e], 0.f));
      }
      int si = (pos << 6) + ((slot ^ (pos & 7)) << 3);
      *(us8*)&hs[si] = o;
    }
    __syncthreads();

    for (int k = 0; k < 9; ++k) {
      const int plb = HALO + wn * 64 + 25 * (k - 4) + l15;
#pragma unroll
      for (int ks = 0; ks < 2; ++ks) {
        bf16x8 af[4], bfr[4];
#pragma unroll
        for (int mi = 0; mi < 4; ++mi) {
          int o = wm * 64 + mi * 16 + l15;
          af[mi] = *(const bf16x8*)&wb2[((k * 16 + cc * 8 + ks * 4 + grp) * 128 + o) * 8];
        }
#pragma unroll
        for (int ni = 0; ni < 4; ++ni) {
          int pl = plb + ni * 16;
          int si = (pl << 6) + (((ks * 4 + grp) ^ (pl & 7)) << 3);
          bfr[ni] = *(const bf16x8*)&hs[si];
        }
#pragma unroll
        for (int mi = 0; mi < 4; ++mi)
#pragma unroll
          for (int ni = 0; ni < 4; ++ni)
            acc[mi][ni] = __builtin_amdgcn_mfma_f32_16x16x32_bf16(
                af[mi], bfr[ni], acc[mi][ni], 0, 0, 0);
      }
    }
  }

  // epilogue: raw conv -> cvb bf16
#pragma unroll
  for (int mi = 0; mi < 4; ++mi) {
#pragma unroll
    for (int ni = 0; ni < 4; ++ni) {
      int pos = p0 + wn * 64 + ni * 16 + l15;
      if (pos < TV) {
#pragma unroll
        for (int r = 0; r < 4; ++r) {
          int o = wm * 64 + mi * 16 + grp * 4 + r;
          cvb[((long long)(b * COUT + o)) * TV + pos] = f2bf(acc[mi][ni][r]);
        }
      }
    }
  }
}

// ---------------------------------------------------------------------------
// kF: per-channel sum/sumsq of cvb (bf16 [b][c][pos]). grid (8,128).
// ---------------------------------------------------------------------------
__global__ __launch_bounds__(256) void kF(const unsigned short* __restrict__ cvb,
                                          float* __restrict__ part) {
  __shared__ float red[256];
  const int tid = threadIdx.x, p = blockIdx.x, c = blockIdx.y;
  float s0 = 0, s1 = 0;
  for (int b = 0; b < B; ++b) {
    const us4* plane = (const us4*)&cvb[((long long)(b * COUT + c)) * TV];
    for (int u = p * 256 + tid; u < 1875; u += 2048) {
      us4 v = plane[u];
#pragma unroll
      for (int e = 0; e < 4; ++e) {
        float f = bf2f(v[e]);
        s0 += f; s1 += f * f;
      }
    }
  }
  float vals[2] = {s0, s1};
  for (int j = 0; j < 2; ++j) {
    red[tid] = vals[j];
    __syncthreads();
    for (int sft = 128; sft > 0; sft >>= 1) {
      if (tid < sft) red[tid] += red[tid + sft];
      __syncthreads();
    }
    if (tid == 0) part[(c * 8 + p) * 2 + j] = red[0];
    __syncthreads();
  }
}

// ---------------------------------------------------------------------------
// kG: finalize temporal BN.
// ---------------------------------------------------------------------------
__global__ __launch_bounds__(128) void kG(
    const float* __restrict__ part,
    const float* __restrict__ g_t, const float* __restrict__ be_t,
    float* __restrict__ scales)
{
  const int c = threadIdx.x;
  float s0 = 0, s1 = 0;
  for (int p = 0; p < 8; ++p) {
    const float* q = &part[(c * 8 + p) * 2];
    s0 += q[0]; s1 += q[1];
  }
  const float n = (float)NPC;
  float m = s0 / n, v = s1 / n - m * m;
  float sc = g_t[c] * rsqrtf(v + 1e-5f);
  scales[512 + c] = sc;
  scales[640 + c] = be_t[c] - m * sc;
}

// ---------------------------------------------------------------------------
// kH: out = relu(cvb*sc_t+sh_t + resb*sc_r+sh_r). Plane-based: grid 4096,
// us4 bf16 loads + float4 stores (all aligned).
// ---------------------------------------------------------------------------
__global__ __launch_bounds__(256) void kH(
    const unsigned short* __restrict__ cvb, const unsigned short* __restrict__ resb,
    const float* __restrict__ scales, float* __restrict__ out)
{
  const int plane = blockIdx.x;          // b*128 + c
  const int c = plane & 127;
  const float sct = scales[512 + c], sht = scales[640 + c];
  const float scr = scales[c],       shr = scales[128 + c];
  const us4* cp = (const us4*)&cvb[(long long)plane * TV];
  const us4* rp = (const us4*)&resb[(long long)plane * TV];
  float* op = &out[(long long)plane * TV];
  for (int u = threadIdx.x; u < 1875; u += 256) {
    us4 o4 = cp[u], r4 = rp[u];
    float4 y;
    y.x = fmaxf(bf2f(o4[0]) * sct + sht + bf2f(r4[0]) * scr + shr, 0.f);
    y.y = fmaxf(bf2f(o4[1]) * sct + sht + bf2f(r4[1]) * scr + shr, 0.f);
    y.z = fmaxf(bf2f(o4[2]) * sct + sht + bf2f(r4[2]) * scr + shr, 0.f);
    y.w = fmaxf(bf2f(o4[3]) * sct + sht + bf2f(r4[3]) * scr + shr, 0.f);
    *(float4*)&op[u * 4] = y;
  }
}

// ---------------------------------------------------------------------------
extern "C" void kernel_launch(void* const* d_in, const int* in_sizes, int n_in,
                              void* d_out, int out_size, void* d_ws, size_t ws_size,
                              hipStream_t stream) {
  const float* x     = (const float*)d_in[0];
  const float* A_hat = (const float*)d_in[1];
  const float* w_sp  = (const float*)d_in[2];
  const float* g_sp  = (const float*)d_in[4];
  const float* be_sp = (const float*)d_in[5];
  const float* w_t   = (const float*)d_in[6];
  const float* g_t   = (const float*)d_in[8];
  const float* be_t  = (const float*)d_in[9];
  const float* w_r   = (const float*)d_in[10];
  const float* g_r   = (const float*)d_in[12];
  const float* be_r  = (const float*)d_in[13];
  float* out = (float*)d_out;

  // workspace carving (all bf16 intermediates)
  char* base = (char*)d_ws;
  unsigned short* resb = (unsigned short*)base;                        // 61.44 MB
  unsigned short* h    = (unsigned short*)(base + (size_t)TOTAL * 2);  // 61.44 MB
  unsigned short* cvb  = (unsigned short*)(base + (size_t)TOTAL * 4);  // 61.44 MB
  unsigned short* wb2  = (unsigned short*)(base + (size_t)TOTAL * 6);  // 294912 B
  unsigned short* wrs2 = wb2 + 147456;                                 // 32768 B
  unsigned short* bdt  = wrs2 + 16384;                                 // 28672 B
  float* part_h = (float*)(bdt + 14336);                               // 64 KB
  float* part_r = part_h + 16384;                                      //  8 KB
  float* part_t = part_r + 2048;                                       //  8 KB
  float* scales = part_t + 2048;                                       //  3 KB

  // weight / graph-matrix prep
  kWT<<<576, 256, 0, stream>>>(w_t, wb2);
  kW2<<<64,  256, 0, stream>>>(w_r, w_sp, wrs2);
  kWB<<<56,  256, 0, stream>>>(A_hat, bdt);
  // spatial front-end: mix + dual channel GEMM, all MFMA
  kA4<<<dim3(75, 32), 256, 0, stream>>>(x, bdt, wrs2, resb, h);
  // BN stats (sp + res)
  kBh<<<dim3(64, 4), 256, 0, stream>>>(h, part_h);
  kBr<<<dim3(8, 128), 256, 0, stream>>>(resb, part_r);
  kC2<<<1, 128, 0, stream>>>(part_h, part_r, g_r, be_r, g_sp, be_sp, scales);
  // temporal conv (BN_s+ReLU fused in staging)
  kE4<<<dim3(59, 32), 256, 0, stream>>>(h, wb2, scales, cvb);
  // BN stats temporal
  kF<<<dim3(8, 128), 256, 0, stream>>>(cvb, part_t);
  kG<<<1, 128, 0, stream>>>(part_t, g_t, be_t, scales);
  // fused epilogue
  kH<<<4096, 256, 0, stream>>>(cvb, resb, scales, out);
}